// Round 6
// baseline (397.027 us; speedup 1.0000x reference)
//
#include <hip/hip_runtime.h>

#define IN_CH 128
#define HID 16
#define SHIFT 8            // bucket = dst >> 8  (256 nodes per bucket)
#define CA 16384           // edges per block in pass-A kernels
#define SCAN_B 512
#define MAXNB 512

// native clang vector types accepted by __builtin_nontemporal_*
typedef int   vint4  __attribute__((ext_vector_type(4)));
typedef float vfloat2 __attribute__((ext_vector_type(2)));

// ============ per-node degree (edge-only) ============

__global__ void deg_count_kernel(const int* __restrict__ col, int* __restrict__ deg, int e) {
    int i = blockIdx.x * blockDim.x + threadIdx.x;
    if (i < e) atomicAdd(&deg[col[i]], 1);
}

// ============ scan of PADDED degrees -> row_ptr (pad each list to mult of 8) ============

__global__ __launch_bounds__(SCAN_B) void scanD1_kernel(
    const int* __restrict__ deg, int* __restrict__ row_ptr, int* __restrict__ bsum, int n) {
    __shared__ int s[SCAN_B];
    int t = threadIdx.x;
    int i = blockIdx.x * SCAN_B + t;
    int v = (i < n) ? ((deg[i] + 7) & ~7) : 0;
    s[t] = v;
    __syncthreads();
    for (int off = 1; off < SCAN_B; off <<= 1) {
        int a = (t >= off) ? s[t - off] : 0;
        __syncthreads();
        s[t] += a;
        __syncthreads();
    }
    if (i < n) row_ptr[i] = s[t] - v;
    if (t == SCAN_B - 1) bsum[blockIdx.x] = s[t];
}

__global__ __launch_bounds__(SCAN_B) void scan2_kernel(int* __restrict__ bsum, int nb) {
    __shared__ int s[SCAN_B];
    int t = threadIdx.x;
    int v = (t < nb) ? bsum[t] : 0;
    s[t] = v;
    __syncthreads();
    for (int off = 1; off < SCAN_B; off <<= 1) {
        int a = (t >= off) ? s[t - off] : 0;
        __syncthreads();
        s[t] += a;
        __syncthreads();
    }
    if (t < nb) bsum[t] = s[t] - v;
}

__global__ void scanD3_kernel(int* __restrict__ row_ptr, const int* __restrict__ bsum,
                              const int* __restrict__ deg, float* __restrict__ dinv, int n) {
    int i = blockIdx.x * blockDim.x + threadIdx.x;
    if (i >= n) return;
    int rp = row_ptr[i] + bsum[i >> 9];   // SCAN_B == 512
    row_ptr[i] = rp;
    dinv[i] = rsqrtf((float)(deg[i] + 1));   // +1 self-loop
    if (i == n - 1) row_ptr[n] = rp + ((deg[i] + 7) & ~7);
    if (i == 0) dinv[n] = 0.0f;              // dummy row
}

// ============ pass A1: per-block per-bucket histogram ============

__global__ __launch_bounds__(256) void histA_kernel(
    const int* __restrict__ col, int* __restrict__ histT, int e, int NB, int nba) {
    __shared__ int hist[MAXNB];
    int j = blockIdx.x, t = threadIdx.x;
    for (int b = t; b < NB; b += 256) hist[b] = 0;
    __syncthreads();
    int e4 = e >> 2;
    const int4* c4p = (const int4*)col;
#pragma unroll
    for (int k = 0; k < CA / 1024; ++k) {
        int i4 = j * (CA / 4) + k * 256 + t;
        if (i4 < e4) {
            int4 c = c4p[i4];
            atomicAdd(&hist[c.x >> SHIFT], 1);
            atomicAdd(&hist[c.y >> SHIFT], 1);
            atomicAdd(&hist[c.z >> SHIFT], 1);
            atomicAdd(&hist[c.w >> SHIFT], 1);
        }
    }
    if (j == gridDim.x - 1) {
        for (int i = (e & ~3) + t; i < e; i += 256) atomicAdd(&hist[col[i] >> SHIFT], 1);
    }
    __syncthreads();
    for (int b = t; b < NB; b += 256) histT[b * nba + j] = hist[b];
}

// ============ generic 2-level exclusive scan (for histT) ============

__global__ __launch_bounds__(SCAN_B) void scan1_kernel(
    const int* __restrict__ in, int* __restrict__ out, int* __restrict__ bsum, int m) {
    __shared__ int s[SCAN_B];
    int t = threadIdx.x;
    int i = blockIdx.x * SCAN_B + t;
    int v = (i < m) ? in[i] : 0;
    s[t] = v;
    __syncthreads();
    for (int off = 1; off < SCAN_B; off <<= 1) {
        int a = (t >= off) ? s[t - off] : 0;
        __syncthreads();
        s[t] += a;
        __syncthreads();
    }
    if (i < m) out[i] = s[t] - v;
    if (t == SCAN_B - 1) bsum[blockIdx.x] = s[t];
}

__global__ void scanadd_kernel(int* __restrict__ data, const int* __restrict__ bsum, int m) {
    int i = blockIdx.x * blockDim.x + threadIdx.x;
    if (i < m) data[i] += bsum[i >> 9];
}

// ============ pass A3: scatter edges into bucket runs in tmp ============

__global__ __launch_bounds__(256) void scatterA_kernel(
    const int* __restrict__ row, const int* __restrict__ col,
    const int* __restrict__ histTs, int* __restrict__ tmp, int e, int NB, int nba) {
    __shared__ int cur[MAXNB];
    int j = blockIdx.x, t = threadIdx.x;
    for (int b = t; b < NB; b += 256) cur[b] = histTs[b * nba + j];
    __syncthreads();
    int e4 = e >> 2;
    const int4* c4p = (const int4*)col;
    const int4* r4p = (const int4*)row;
#pragma unroll
    for (int k = 0; k < CA / 1024; ++k) {
        int i4 = j * (CA / 4) + k * 256 + t;
        if (i4 < e4) {
            int4 c = c4p[i4];
            int4 r = r4p[i4];
            int pos;
            pos = atomicAdd(&cur[c.x >> SHIFT], 1); tmp[pos] = (r.x << 8) | (c.x & 255);
            pos = atomicAdd(&cur[c.y >> SHIFT], 1); tmp[pos] = (r.y << 8) | (c.y & 255);
            pos = atomicAdd(&cur[c.z >> SHIFT], 1); tmp[pos] = (r.z << 8) | (c.z & 255);
            pos = atomicAdd(&cur[c.w >> SHIFT], 1); tmp[pos] = (r.w << 8) | (c.w & 255);
        }
    }
    if (j == gridDim.x - 1) {
        for (int i = (e & ~3) + t; i < e; i += 256) {
            int c = col[i], r = row[i];
            int pos = atomicAdd(&cur[c >> SHIFT], 1);
            tmp[pos] = (r << 8) | (c & 255);
        }
    }
}

// ============ pass B: place edges at padded row_ptr positions; pad tails with dummy n ============

__global__ __launch_bounds__(256) void bucketB_kernel(
    const int* __restrict__ tmp, const int* __restrict__ histTs,
    const int* __restrict__ row_ptr, int* __restrict__ pk,
    int n, int e, int NB, int nba) {
    __shared__ int cur[256];
    int b = blockIdx.x, t = threadIdx.x;
    int bs = histTs[b * nba];
    int be = (b + 1 < NB) ? histTs[(b + 1) * nba] : e;
    int node = (b << SHIFT) + t;
    int rp_s = (node < n) ? row_ptr[node] : 0;
    int rp_e = (node < n) ? row_ptr[node + 1] : 0;
    cur[t] = rp_s;
    __syncthreads();
    for (int i = bs + t; i < be; i += 256) {
        int u = tmp[i];
        int pos = atomicAdd(&cur[u & 255], 1);
        pk[pos] = u >> 8;
    }
    __syncthreads();
    for (int p = cur[t]; p < rp_e; ++p) pk[p] = n;   // <=7 dummy pads per node
}

// ============ layer 1 dense: hs = dinv * (x @ W1), split into A/B half-tables ============

__global__ __launch_bounds__(256) void gemm1_kernel(
    const float* __restrict__ x, const float* __restrict__ W1,
    const float* __restrict__ dinv, float* __restrict__ hsA, float* __restrict__ hsB, int n) {
    __shared__ float sx[16][IN_CH + 4];
    __shared__ float sw[IN_CH][HID];
    int t = threadIdx.x;
#pragma unroll
    for (int i = t; i < 512; i += 256) {
        float4 v = ((const float4*)W1)[i];
        int rr = i >> 2, cc = (i & 3) << 2;
        sw[rr][cc] = v.x; sw[rr][cc + 1] = v.y; sw[rr][cc + 2] = v.z; sw[rr][cc + 3] = v.w;
    }
    int row0 = blockIdx.x * 16;
#pragma unroll
    for (int i = t; i < 512; i += 256) {
        int r = i >> 5, k4 = (i & 31) << 2;
        int gr = row0 + r;
        float4 v = make_float4(0.f, 0.f, 0.f, 0.f);
        if (gr < n) v = *(const float4*)(x + (size_t)gr * IN_CH + k4);
        *(float4*)&sx[r][k4] = v;
    }
    __syncthreads();
    int r = t >> 4, c = t & 15;
    float acc = 0.0f;
#pragma unroll
    for (int k = 0; k < IN_CH; ++k) acc += sx[r][k] * sw[k][c];
    int gr = row0 + r;
    if (gr <= n) {
        float dg = (gr < n) ? dinv[gr] : 0.0f;   // row n := 0 (dummy)
        float v = acc * dg;
        if (c < 8) hsA[(size_t)gr * 8 + c] = v;
        else       hsB[(size_t)gr * 8 + (c - 8)] = v;
    }
}

// ============ half-channel aggregation: conv[g] = tab[g] + sum_src tab[src] ============
// 4 lanes/node, float2/lane (32B rows); rows padded to mult of 8 -> exact unroll-8;
// pk/row_ptr non-temporal so the 3.2MB table stays L2-resident.

__global__ __launch_bounds__(256) void agg_kernel(
    const float* __restrict__ tab, const int* __restrict__ row_ptr,
    const int* __restrict__ pk, float* __restrict__ conv, int n) {
    int t = threadIdx.x;
    int node = blockIdx.x * 64 + (t >> 2);
    int sub = t & 3;
    if (node >= n) return;
    const float2* h2 = (const float2*)tab;
    float2 self = h2[(size_t)node * 4 + sub];
    float cx = self.x, cy = self.y;
    int beg = __builtin_nontemporal_load(row_ptr + node);
    int end = __builtin_nontemporal_load(row_ptr + node + 1);
    for (int j = beg; j < end; j += 8) {
        vint4 p0 = __builtin_nontemporal_load((const vint4*)(pk + j));
        vint4 p1 = __builtin_nontemporal_load((const vint4*)(pk + j + 4));
        float2 v0 = h2[(size_t)p0.x * 4 + sub];
        float2 v1 = h2[(size_t)p0.y * 4 + sub];
        float2 v2 = h2[(size_t)p0.z * 4 + sub];
        float2 v3 = h2[(size_t)p0.w * 4 + sub];
        float2 v4 = h2[(size_t)p1.x * 4 + sub];
        float2 v5 = h2[(size_t)p1.y * 4 + sub];
        float2 v6 = h2[(size_t)p1.z * 4 + sub];
        float2 v7 = h2[(size_t)p1.w * 4 + sub];
        cx += ((v0.x + v1.x) + (v2.x + v3.x)) + ((v4.x + v5.x) + (v6.x + v7.x));
        cy += ((v0.y + v1.y) + (v2.y + v3.y)) + ((v4.y + v5.y) + (v6.y + v7.y));
    }
    vfloat2 o;
    o.x = cx; o.y = cy;
    __builtin_nontemporal_store(o, (vfloat2*)conv + (size_t)node * 4 + sub);
}

// ============ inter-layer MLP: hs2 = dinv * ( relu(dinv*conv1 + b1) @ W2 ) ============

__global__ __launch_bounds__(256) void mlp_kernel(
    const float* __restrict__ cA, const float* __restrict__ cB,
    const float* __restrict__ dinv, const float* __restrict__ b1,
    const float* __restrict__ W2, float* __restrict__ hA, float* __restrict__ hB, int n) {
    __shared__ float sw[HID][HID];
    __shared__ float sb[HID];
    int t = threadIdx.x;
    sw[t >> 4][t & 15] = W2[t];           // 256 == HID*HID
    if (t < HID) sb[t] = b1[t];
    __syncthreads();
    int i = blockIdx.x * 256 + t;
    if (i > n) return;
    float4* oA = (float4*)(hA + (size_t)i * 8);
    float4* oB = (float4*)(hB + (size_t)i * 8);
    if (i == n) {   // dummy row := 0
        float4 z = make_float4(0.f, 0.f, 0.f, 0.f);
        oA[0] = z; oA[1] = z; oB[0] = z; oB[1] = z;
        return;
    }
    const float4* a4 = (const float4*)(cA + (size_t)i * 8);
    const float4* b4 = (const float4*)(cB + (size_t)i * 8);
    float4 r0 = a4[0], r1 = a4[1], r2 = b4[0], r3 = b4[1];
    float dg = dinv[i];
    float a[HID];
    a[0]  = fmaxf(fmaf(r0.x, dg, sb[0]),  0.f);
    a[1]  = fmaxf(fmaf(r0.y, dg, sb[1]),  0.f);
    a[2]  = fmaxf(fmaf(r0.z, dg, sb[2]),  0.f);
    a[3]  = fmaxf(fmaf(r0.w, dg, sb[3]),  0.f);
    a[4]  = fmaxf(fmaf(r1.x, dg, sb[4]),  0.f);
    a[5]  = fmaxf(fmaf(r1.y, dg, sb[5]),  0.f);
    a[6]  = fmaxf(fmaf(r1.z, dg, sb[6]),  0.f);
    a[7]  = fmaxf(fmaf(r1.w, dg, sb[7]),  0.f);
    a[8]  = fmaxf(fmaf(r2.x, dg, sb[8]),  0.f);
    a[9]  = fmaxf(fmaf(r2.y, dg, sb[9]),  0.f);
    a[10] = fmaxf(fmaf(r2.z, dg, sb[10]), 0.f);
    a[11] = fmaxf(fmaf(r2.w, dg, sb[11]), 0.f);
    a[12] = fmaxf(fmaf(r3.x, dg, sb[12]), 0.f);
    a[13] = fmaxf(fmaf(r3.y, dg, sb[13]), 0.f);
    a[14] = fmaxf(fmaf(r3.z, dg, sb[14]), 0.f);
    a[15] = fmaxf(fmaf(r3.w, dg, sb[15]), 0.f);
    float o[HID];
#pragma unroll
    for (int c = 0; c < HID; ++c) {
        float acc = 0.f;
#pragma unroll
        for (int k = 0; k < HID; ++k) acc += a[k] * sw[k][c];
        o[c] = acc * dg;
    }
    oA[0] = make_float4(o[0],  o[1],  o[2],  o[3]);
    oA[1] = make_float4(o[4],  o[5],  o[6],  o[7]);
    oB[0] = make_float4(o[8],  o[9],  o[10], o[11]);
    oB[1] = make_float4(o[12], o[13], o[14], o[15]);
}

// ============ head: out = relu(dinv*conv2 + b2) . Wl + bl ============

__global__ __launch_bounds__(256) void head_kernel(
    const float* __restrict__ cA, const float* __restrict__ cB,
    const float* __restrict__ dinv, const float* __restrict__ b2,
    const float* __restrict__ Wl, const float* __restrict__ bl,
    float* __restrict__ out, int n) {
    __shared__ float sb[HID];
    __shared__ float swl[HID];
    __shared__ float sbl;
    int t = threadIdx.x;
    if (t < HID) { sb[t] = b2[t]; swl[t] = Wl[t]; }
    if (t == 0) sbl = bl[0];
    __syncthreads();
    int i = blockIdx.x * 256 + t;
    if (i >= n) return;
    const float4* a4 = (const float4*)(cA + (size_t)i * 8);
    const float4* b4 = (const float4*)(cB + (size_t)i * 8);
    float4 r0 = a4[0], r1 = a4[1], r2 = b4[0], r3 = b4[1];
    float dg = dinv[i];
    float p = sbl;
    p += fmaxf(fmaf(r0.x, dg, sb[0]),  0.f) * swl[0];
    p += fmaxf(fmaf(r0.y, dg, sb[1]),  0.f) * swl[1];
    p += fmaxf(fmaf(r0.z, dg, sb[2]),  0.f) * swl[2];
    p += fmaxf(fmaf(r0.w, dg, sb[3]),  0.f) * swl[3];
    p += fmaxf(fmaf(r1.x, dg, sb[4]),  0.f) * swl[4];
    p += fmaxf(fmaf(r1.y, dg, sb[5]),  0.f) * swl[5];
    p += fmaxf(fmaf(r1.z, dg, sb[6]),  0.f) * swl[6];
    p += fmaxf(fmaf(r1.w, dg, sb[7]),  0.f) * swl[7];
    p += fmaxf(fmaf(r2.x, dg, sb[8]),  0.f) * swl[8];
    p += fmaxf(fmaf(r2.y, dg, sb[9]),  0.f) * swl[9];
    p += fmaxf(fmaf(r2.z, dg, sb[10]), 0.f) * swl[10];
    p += fmaxf(fmaf(r2.w, dg, sb[11]), 0.f) * swl[11];
    p += fmaxf(fmaf(r3.x, dg, sb[12]), 0.f) * swl[12];
    p += fmaxf(fmaf(r3.y, dg, sb[13]), 0.f) * swl[13];
    p += fmaxf(fmaf(r3.z, dg, sb[14]), 0.f) * swl[14];
    p += fmaxf(fmaf(r3.w, dg, sb[15]), 0.f) * swl[15];
    out[i] = p;
}

extern "C" void kernel_launch(void* const* d_in, const int* in_sizes, int n_in,
                              void* d_out, int out_size, void* d_ws, size_t ws_size,
                              hipStream_t stream) {
    const float* x  = (const float*)d_in[0];
    const int*   ei = (const int*)d_in[1];
    const float* W1 = (const float*)d_in[2];
    const float* b1 = (const float*)d_in[3];
    const float* W2 = (const float*)d_in[4];
    const float* b2 = (const float*)d_in[5];
    const float* Wl = (const float*)d_in[6];
    const float* bl = (const float*)d_in[7];

    int n = in_sizes[0] / IN_CH;
    int e = in_sizes[1] / 2;
    const int* row = ei;        // sources
    const int* col = ei + e;    // targets

    int NB  = (n + 255) >> SHIFT;            // 391
    int nba = (e + CA - 1) / CA;             // 196
    int m   = NB * nba;
    int nsb = (m + SCAN_B - 1) / SCAN_B;     // 150 (<=512)
    int nbd = (n + SCAN_B - 1) / SCAN_B;     // 196 (<=512)

    char* ws = (char*)d_ws;
    size_t off = 0;
    auto alloc = [&](size_t bytes) -> void* {
        void* p = ws + off;
        off = (off + bytes + 255) & ~(size_t)255;
        return p;
    };

    size_t tabf = (size_t)(n + 1) * 8;       // floats per half-table

    int*   deg     = (int*)alloc((size_t)n * 4);
    int*   row_ptr = (int*)alloc(((size_t)n + 1) * 4);
    float* dinv    = (float*)alloc(((size_t)n + 1) * 4);
    int*   bsumD   = (int*)alloc((size_t)nbd * 4);
    int*   histT   = (int*)alloc((size_t)m * 4);
    int*   histTs  = (int*)alloc((size_t)m * 4);
    int*   bsum2   = (int*)alloc((size_t)nsb * 4);
    int*   pk      = (int*)alloc(((size_t)e + 8 * (size_t)n + 64) * 4);
    // overlay region: tmp (edge staging) dies before the 4 half-tables are born
    size_t region = (size_t)e * 4;
    size_t tables = 4 * tabf * 4;
    char*  R      = (char*)alloc(region > tables ? region : tables);
    int*   tmp    = (int*)R;
    float* hsA    = (float*)R;               // also hs2A after mlp
    float* hsB    = hsA + tabf;              // also hs2B
    float* cvA    = hsB + tabf;              // conv1A, then conv2A
    float* cvB    = cvA + tabf;              // conv1B, then conv2B

    dim3 blk(256);
    dim3 gN((n + 255) / 256);
    dim3 gN1((n + 1 + 255) / 256);
    dim3 gE((e + 255) / 256);
    dim3 gG((n + 1 + 15) / 16);
    dim3 gA((n + 63) / 64);

    // ---- CSR build (padded, dst-sorted) ----
    (void)hipMemsetAsync(deg, 0, (size_t)n * 4, stream);
    hipLaunchKernelGGL(deg_count_kernel, gE, blk, 0, stream, col, deg, e);
    hipLaunchKernelGGL(scanD1_kernel, dim3(nbd), dim3(SCAN_B), 0, stream, deg, row_ptr, bsumD, n);
    hipLaunchKernelGGL(scan2_kernel,  dim3(1),   dim3(SCAN_B), 0, stream, bsumD, nbd);
    hipLaunchKernelGGL(scanD3_kernel, gN, blk, 0, stream, row_ptr, bsumD, deg, dinv, n);
    hipLaunchKernelGGL(histA_kernel,  dim3(nba), blk, 0, stream, col, histT, e, NB, nba);
    hipLaunchKernelGGL(scan1_kernel,  dim3(nsb), dim3(SCAN_B), 0, stream, histT, histTs, bsum2, m);
    hipLaunchKernelGGL(scan2_kernel,  dim3(1),   dim3(SCAN_B), 0, stream, bsum2, nsb);
    hipLaunchKernelGGL(scanadd_kernel, dim3((m + 255) / 256), blk, 0, stream, histTs, bsum2, m);
    hipLaunchKernelGGL(scatterA_kernel, dim3(nba), blk, 0, stream, row, col, histTs, tmp, e, NB, nba);
    hipLaunchKernelGGL(bucketB_kernel,  dim3(NB),  blk, 0, stream, tmp, histTs, row_ptr, pk, n, e, NB, nba);

    // ---- network ----
    hipLaunchKernelGGL(gemm1_kernel, gG, blk, 0, stream, x, W1, dinv, hsA, hsB, n);
    // layer-1 aggregation, one 3.2MB half-table at a time (L2-resident)
    hipLaunchKernelGGL(agg_kernel, gA, blk, 0, stream, hsA, row_ptr, pk, cvA, n);
    hipLaunchKernelGGL(agg_kernel, gA, blk, 0, stream, hsB, row_ptr, pk, cvB, n);
    // inter-layer MLP (overwrites hsA/hsB with hs2A/hs2B)
    hipLaunchKernelGGL(mlp_kernel, gN1, blk, 0, stream, cvA, cvB, dinv, b1, W2, hsA, hsB, n);
    // layer-2 aggregation (overwrites cvA/cvB with conv2)
    hipLaunchKernelGGL(agg_kernel, gA, blk, 0, stream, hsA, row_ptr, pk, cvA, n);
    hipLaunchKernelGGL(agg_kernel, gA, blk, 0, stream, hsB, row_ptr, pk, cvB, n);
    // head
    hipLaunchKernelGGL(head_kernel, gN, blk, 0, stream, cvA, cvB, dinv, b2, Wl, bl, (float*)d_out, n);
}

// Round 7
// 205.794 us; speedup vs baseline: 1.9292x; 1.9292x over previous
//
#include <hip/hip_runtime.h>

#define IN_CH 128
#define HID 16
#define SHIFT 8            // bucket = dst >> 8  (256 nodes per bucket)
#define CA 16384           // edges per block in pass-A kernels
#define SCAN_B 512
#define MAXNB 512

// native clang vector types accepted by __builtin_nontemporal_*
typedef int vint4 __attribute__((ext_vector_type(4)));

// ============ pass A1: per-block per-bucket histogram ============

__global__ __launch_bounds__(256) void histA_kernel(
    const int* __restrict__ col, int* __restrict__ histT, int e, int NB, int nba) {
    __shared__ int hist[MAXNB];
    int j = blockIdx.x, t = threadIdx.x;
    for (int b = t; b < NB; b += 256) hist[b] = 0;
    __syncthreads();
    int e4 = e >> 2;
    const int4* c4p = (const int4*)col;
#pragma unroll
    for (int k = 0; k < CA / 1024; ++k) {
        int i4 = j * (CA / 4) + k * 256 + t;
        if (i4 < e4) {
            int4 c = c4p[i4];
            atomicAdd(&hist[c.x >> SHIFT], 1);
            atomicAdd(&hist[c.y >> SHIFT], 1);
            atomicAdd(&hist[c.z >> SHIFT], 1);
            atomicAdd(&hist[c.w >> SHIFT], 1);
        }
    }
    if (j == gridDim.x - 1) {
        for (int i = (e & ~3) + t; i < e; i += 256) atomicAdd(&hist[col[i] >> SHIFT], 1);
    }
    __syncthreads();
    for (int b = t; b < NB; b += 256) histT[b * nba + j] = hist[b];
}

// ============ generic 2-level exclusive scan (for histT, m elements) ============

__global__ __launch_bounds__(SCAN_B) void scan1_kernel(
    const int* __restrict__ in, int* __restrict__ out, int* __restrict__ bsum, int m) {
    __shared__ int s[SCAN_B];
    int t = threadIdx.x;
    int i = blockIdx.x * SCAN_B + t;
    int v = (i < m) ? in[i] : 0;
    s[t] = v;
    __syncthreads();
    for (int off = 1; off < SCAN_B; off <<= 1) {
        int a = (t >= off) ? s[t - off] : 0;
        __syncthreads();
        s[t] += a;
        __syncthreads();
    }
    if (i < m) out[i] = s[t] - v;
    if (t == SCAN_B - 1) bsum[blockIdx.x] = s[t];
}

__global__ __launch_bounds__(SCAN_B) void scan2_kernel(int* __restrict__ bsum, int nb) {
    __shared__ int s[SCAN_B];
    int t = threadIdx.x;
    int v = (t < nb) ? bsum[t] : 0;
    s[t] = v;
    __syncthreads();
    for (int off = 1; off < SCAN_B; off <<= 1) {
        int a = (t >= off) ? s[t - off] : 0;
        __syncthreads();
        s[t] += a;
        __syncthreads();
    }
    if (t < nb) bsum[t] = s[t] - v;
}

__global__ void scanadd_kernel(int* __restrict__ data, const int* __restrict__ bsum, int m) {
    int i = blockIdx.x * blockDim.x + threadIdx.x;
    if (i < m) data[i] += bsum[i >> 9];   // SCAN_B == 512
}

// ============ pass A3: scatter edges into bucket runs in tmp ============

__global__ __launch_bounds__(256) void scatterA_kernel(
    const int* __restrict__ row, const int* __restrict__ col,
    const int* __restrict__ histTs, int* __restrict__ tmp, int e, int NB, int nba) {
    __shared__ int cur[MAXNB];
    int j = blockIdx.x, t = threadIdx.x;
    for (int b = t; b < NB; b += 256) cur[b] = histTs[b * nba + j];
    __syncthreads();
    int e4 = e >> 2;
    const int4* c4p = (const int4*)col;
    const int4* r4p = (const int4*)row;
#pragma unroll
    for (int k = 0; k < CA / 1024; ++k) {
        int i4 = j * (CA / 4) + k * 256 + t;
        if (i4 < e4) {
            int4 c = c4p[i4];
            int4 r = r4p[i4];
            int pos;
            pos = atomicAdd(&cur[c.x >> SHIFT], 1); tmp[pos] = (r.x << 8) | (c.x & 255);
            pos = atomicAdd(&cur[c.y >> SHIFT], 1); tmp[pos] = (r.y << 8) | (c.y & 255);
            pos = atomicAdd(&cur[c.z >> SHIFT], 1); tmp[pos] = (r.z << 8) | (c.z & 255);
            pos = atomicAdd(&cur[c.w >> SHIFT], 1); tmp[pos] = (r.w << 8) | (c.w & 255);
        }
    }
    if (j == gridDim.x - 1) {
        for (int i = (e & ~3) + t; i < e; i += 256) {
            int c = col[i], r = row[i];
            int pos = atomicAdd(&cur[c >> SHIFT], 1);
            tmp[pos] = (r << 8) | (c & 255);
        }
    }
}

// ============ pass C: per-bucket padded degree/offsets (NO global atomics) ============
// locoff(->row_ptr)[node] = padded exclusive offset within bucket; pcnt[node] = padded deg;
// bktTot[b] = bucket padded total; dinv from true count.

__global__ __launch_bounds__(256) void bucketC_kernel(
    const int* __restrict__ tmp, const int* __restrict__ histTs,
    int* __restrict__ row_ptr, int* __restrict__ pcnt, int* __restrict__ bktTot,
    float* __restrict__ dinv, int n, int e, int NB, int nba) {
    __shared__ int hcnt[256];
    __shared__ int scn[256];
    int b = blockIdx.x, t = threadIdx.x;
    int bs = histTs[b * nba];
    int be = (b + 1 < NB) ? histTs[(b + 1) * nba] : e;
    hcnt[t] = 0;
    __syncthreads();
    for (int i = bs + t; i < be; i += 256) atomicAdd(&hcnt[tmp[i] & 255], 1);
    __syncthreads();
    int cnt = hcnt[t];
    int pc = (cnt + 7) & ~7;
    scn[t] = pc;
    __syncthreads();
    for (int off = 1; off < 256; off <<= 1) {
        int a = (t >= off) ? scn[t - off] : 0;
        __syncthreads();
        scn[t] += a;
        __syncthreads();
    }
    int excl = scn[t] - pc;
    int node = (b << SHIFT) + t;
    if (node < n) {
        row_ptr[node] = excl;          // local offset for now
        pcnt[node] = pc;
        dinv[node] = rsqrtf((float)(cnt + 1));   // +1 self-loop
    }
    if (t == 255) bktTot[b] = scn[255];
    if (b == 0 && t == 0) dinv[n] = 0.0f;        // dummy row
}

// exclusive scan of bucket padded totals (NB <= 512), writes grand total to row_ptr[n]
__global__ __launch_bounds__(SCAN_B) void scanB_kernel(
    int* __restrict__ bktTot, int* __restrict__ row_ptr, int NB, int n) {
    __shared__ int s[SCAN_B];
    int t = threadIdx.x;
    int v = (t < NB) ? bktTot[t] : 0;
    s[t] = v;
    __syncthreads();
    for (int off = 1; off < SCAN_B; off <<= 1) {
        int a = (t >= off) ? s[t - off] : 0;
        __syncthreads();
        s[t] += a;
        __syncthreads();
    }
    if (t < NB) bktTot[t] = s[t] - v;
    if (t == SCAN_B - 1) row_ptr[n] = s[t];
}

// ============ pass D: finalize row_ptr, scatter into pk, pad tails with dummy n ============

__global__ __launch_bounds__(256) void bucketD_kernel(
    const int* __restrict__ tmp, const int* __restrict__ histTs,
    const int* __restrict__ bktTot, const int* __restrict__ pcnt,
    int* __restrict__ row_ptr, int* __restrict__ pk,
    int n, int e, int NB, int nba) {
    __shared__ int cur[256];
    int b = blockIdx.x, t = threadIdx.x;
    int bs = histTs[b * nba];
    int be = (b + 1 < NB) ? histTs[(b + 1) * nba] : e;
    int node = (b << SHIFT) + t;
    int rp = 0, pc = 0;
    if (node < n) {
        rp = bktTot[b] + row_ptr[node];   // base + local offset
        pc = pcnt[node];
        row_ptr[node] = rp;
    }
    cur[t] = rp;
    __syncthreads();
    for (int i = bs + t; i < be; i += 256) {
        int u = tmp[i];
        int pos = atomicAdd(&cur[u & 255], 1);
        pk[pos] = u >> 8;
    }
    __syncthreads();
    int pe = rp + pc;
    for (int p = cur[t]; p < pe; ++p) pk[p] = n;   // <=7 dummy pads per node
}

// ============ layer 1 dense: hs = dinv * (x @ W1)  (row n := 0) ============

__global__ __launch_bounds__(256) void gemm1_kernel(
    const float* __restrict__ x, const float* __restrict__ W1,
    const float* __restrict__ dinv, float* __restrict__ hs, int n) {
    __shared__ float sx[16][IN_CH + 4];
    __shared__ float sw[IN_CH][HID];
    int t = threadIdx.x;
#pragma unroll
    for (int i = t; i < 512; i += 256) {
        float4 v = ((const float4*)W1)[i];
        int rr = i >> 2, cc = (i & 3) << 2;
        sw[rr][cc] = v.x; sw[rr][cc + 1] = v.y; sw[rr][cc + 2] = v.z; sw[rr][cc + 3] = v.w;
    }
    int row0 = blockIdx.x * 16;
#pragma unroll
    for (int i = t; i < 512; i += 256) {
        int r = i >> 5, k4 = (i & 31) << 2;
        int gr = row0 + r;
        float4 v = make_float4(0.f, 0.f, 0.f, 0.f);
        if (gr < n) v = *(const float4*)(x + (size_t)gr * IN_CH + k4);
        *(float4*)&sx[r][k4] = v;
    }
    __syncthreads();
    int r = t >> 4, c = t & 15;
    float acc = 0.0f;
#pragma unroll
    for (int k = 0; k < IN_CH; ++k) acc += sx[r][k] * sw[k][c];
    int gr = row0 + r;
    if (gr <= n) {
        float dg = (gr < n) ? dinv[gr] : 0.0f;
        hs[(size_t)gr * HID + c] = acc * dg;
    }
}

// ============ aggregation, full 64B rows, padded unroll-8, fused epilogues ============
// acc = hs[g] + sum_src hs[src] (8 float4 gathers in flight per lane)
// agg1 epilogue: hs2 = dinv * ( relu(dinv*acc + b1) @ W2 )
// agg2 epilogue: out = relu(dinv*acc + b2) . Wl + bl

__global__ __launch_bounds__(256) void agg1_kernel(
    const float* __restrict__ hs, const int* __restrict__ row_ptr,
    const int* __restrict__ pk, const float* __restrict__ dinv,
    const float* __restrict__ b1, const float* __restrict__ W2,
    float* __restrict__ hs2, int n) {
    int t = threadIdx.x;
    int node = blockIdx.x * 64 + (t >> 2);
    int sub = t & 3;
    if (node >= n) return;   // whole 4-lane group exits together
    const float4* h4 = (const float4*)hs;
    float4 self = h4[(size_t)node * 4 + sub];
    float cx = self.x, cy = self.y, cz = self.z, cw = self.w;
    int beg = __builtin_nontemporal_load(row_ptr + node);
    int end = __builtin_nontemporal_load(row_ptr + node + 1);
    for (int j = beg; j < end; j += 8) {
        vint4 p0 = __builtin_nontemporal_load((const vint4*)(pk + j));
        vint4 p1 = __builtin_nontemporal_load((const vint4*)(pk + j + 4));
        float4 v0 = h4[(size_t)p0.x * 4 + sub];
        float4 v1 = h4[(size_t)p0.y * 4 + sub];
        float4 v2 = h4[(size_t)p0.z * 4 + sub];
        float4 v3 = h4[(size_t)p0.w * 4 + sub];
        float4 v4 = h4[(size_t)p1.x * 4 + sub];
        float4 v5 = h4[(size_t)p1.y * 4 + sub];
        float4 v6 = h4[(size_t)p1.z * 4 + sub];
        float4 v7 = h4[(size_t)p1.w * 4 + sub];
        cx += ((v0.x + v1.x) + (v2.x + v3.x)) + ((v4.x + v5.x) + (v6.x + v7.x));
        cy += ((v0.y + v1.y) + (v2.y + v3.y)) + ((v4.y + v5.y) + (v6.y + v7.y));
        cz += ((v0.z + v1.z) + (v2.z + v3.z)) + ((v4.z + v5.z) + (v6.z + v7.z));
        cw += ((v0.w + v1.w) + (v2.w + v3.w)) + ((v4.w + v5.w) + (v6.w + v7.w));
    }
    float dg = dinv[node];
    float4 b1v = *(const float4*)(b1 + (sub << 2));
    float ax = fmaxf(fmaf(dg, cx, b1v.x), 0.f);
    float ay = fmaxf(fmaf(dg, cy, b1v.y), 0.f);
    float az = fmaxf(fmaf(dg, cz, b1v.z), 0.f);
    float aw = fmaxf(fmaf(dg, cw, b1v.w), 0.f);
    float ox = 0.f, oy = 0.f, oz = 0.f, ow = 0.f;
#pragma unroll
    for (int r = 0; r < 4; ++r) {
        float fx = __shfl_xor(ax, r);
        float fy = __shfl_xor(ay, r);
        float fz = __shfl_xor(az, r);
        float fw = __shfl_xor(aw, r);
        int kb = (sub ^ r) << 2;                       // input-channel block held by partner lane
        const float* wp = W2 + kb * HID + (sub << 2);  // rows kb..kb+3, cols 4*sub..
        float4 w0 = *(const float4*)(wp);
        float4 w1 = *(const float4*)(wp + HID);
        float4 w2 = *(const float4*)(wp + 2 * HID);
        float4 w3 = *(const float4*)(wp + 3 * HID);
        ox += fx * w0.x + fy * w1.x + fz * w2.x + fw * w3.x;
        oy += fx * w0.y + fy * w1.y + fz * w2.y + fw * w3.y;
        oz += fx * w0.z + fy * w1.z + fz * w2.z + fw * w3.z;
        ow += fx * w0.w + fy * w1.w + fz * w2.w + fw * w3.w;
    }
    float4 o; o.x = dg * ox; o.y = dg * oy; o.z = dg * oz; o.w = dg * ow;
    ((float4*)hs2)[(size_t)node * 4 + sub] = o;
}

__global__ __launch_bounds__(256) void agg2_kernel(
    const float* __restrict__ hs2, const int* __restrict__ row_ptr,
    const int* __restrict__ pk, const float* __restrict__ dinv,
    const float* __restrict__ b2, const float* __restrict__ Wl,
    const float* __restrict__ bl, float* __restrict__ out, int n) {
    int t = threadIdx.x;
    int node = blockIdx.x * 64 + (t >> 2);
    int sub = t & 3;
    if (node >= n) return;
    const float4* h4 = (const float4*)hs2;
    float4 self = h4[(size_t)node * 4 + sub];
    float cx = self.x, cy = self.y, cz = self.z, cw = self.w;
    int beg = __builtin_nontemporal_load(row_ptr + node);
    int end = __builtin_nontemporal_load(row_ptr + node + 1);
    for (int j = beg; j < end; j += 8) {
        vint4 p0 = __builtin_nontemporal_load((const vint4*)(pk + j));
        vint4 p1 = __builtin_nontemporal_load((const vint4*)(pk + j + 4));
        float4 v0 = h4[(size_t)p0.x * 4 + sub];
        float4 v1 = h4[(size_t)p0.y * 4 + sub];
        float4 v2 = h4[(size_t)p0.z * 4 + sub];
        float4 v3 = h4[(size_t)p0.w * 4 + sub];
        float4 v4 = h4[(size_t)p1.x * 4 + sub];
        float4 v5 = h4[(size_t)p1.y * 4 + sub];
        float4 v6 = h4[(size_t)p1.z * 4 + sub];
        float4 v7 = h4[(size_t)p1.w * 4 + sub];
        cx += ((v0.x + v1.x) + (v2.x + v3.x)) + ((v4.x + v5.x) + (v6.x + v7.x));
        cy += ((v0.y + v1.y) + (v2.y + v3.y)) + ((v4.y + v5.y) + (v6.y + v7.y));
        cz += ((v0.z + v1.z) + (v2.z + v3.z)) + ((v4.z + v5.z) + (v6.z + v7.z));
        cw += ((v0.w + v1.w) + (v2.w + v3.w)) + ((v4.w + v5.w) + (v6.w + v7.w));
    }
    float dg = dinv[node];
    float4 b2v = *(const float4*)(b2 + (sub << 2));
    float4 wlv = *(const float4*)(Wl + (sub << 2));
    float p = fmaxf(fmaf(dg, cx, b2v.x), 0.f) * wlv.x
            + fmaxf(fmaf(dg, cy, b2v.y), 0.f) * wlv.y
            + fmaxf(fmaf(dg, cz, b2v.z), 0.f) * wlv.z
            + fmaxf(fmaf(dg, cw, b2v.w), 0.f) * wlv.w;
    p += __shfl_xor(p, 1);
    p += __shfl_xor(p, 2);
    if (sub == 0) out[node] = p + bl[0];
}

extern "C" void kernel_launch(void* const* d_in, const int* in_sizes, int n_in,
                              void* d_out, int out_size, void* d_ws, size_t ws_size,
                              hipStream_t stream) {
    const float* x  = (const float*)d_in[0];
    const int*   ei = (const int*)d_in[1];
    const float* W1 = (const float*)d_in[2];
    const float* b1 = (const float*)d_in[3];
    const float* W2 = (const float*)d_in[4];
    const float* b2 = (const float*)d_in[5];
    const float* Wl = (const float*)d_in[6];
    const float* bl = (const float*)d_in[7];

    int n = in_sizes[0] / IN_CH;
    int e = in_sizes[1] / 2;
    const int* row = ei;        // sources
    const int* col = ei + e;    // targets

    int NB  = (n + 255) >> SHIFT;            // 391 (<=512)
    int nba = (e + CA - 1) / CA;             // 196
    int m   = NB * nba;
    int nsb = (m + SCAN_B - 1) / SCAN_B;     // 150 (<=512)

    char* ws = (char*)d_ws;
    size_t off = 0;
    auto alloc = [&](size_t bytes) -> void* {
        void* p = ws + off;
        off = (off + bytes + 255) & ~(size_t)255;
        return p;
    };

    size_t tabf = (size_t)(n + 1) * HID;     // floats per table (incl. dummy row)

    int*   histT   = (int*)alloc((size_t)m * 4);
    int*   histTs  = (int*)alloc((size_t)m * 4);
    int*   bsum2   = (int*)alloc((size_t)nsb * 4);
    int*   row_ptr = (int*)alloc(((size_t)n + 1) * 4);
    int*   pcnt    = (int*)alloc((size_t)n * 4);
    int*   bktTot  = (int*)alloc((size_t)NB * 4);
    float* dinv    = (float*)alloc(((size_t)n + 1) * 4);
    int*   pk      = (int*)alloc(((size_t)e + 8 * (size_t)n + 64) * 4);
    // overlay: tmp (edge staging) dies before the two tables are born
    size_t region = (size_t)e * 4;
    size_t tables = 2 * tabf * 4;
    char*  R      = (char*)alloc(region > tables ? region : tables);
    int*   tmp    = (int*)R;
    float* hs     = (float*)R;
    float* hs2    = hs + tabf;

    dim3 blk(256);
    dim3 gG((n + 1 + 15) / 16);
    dim3 gA((n + 63) / 64);

    // ---- CSR build (padded, dst-sorted, zero global atomics) ----
    hipLaunchKernelGGL(histA_kernel,    dim3(nba), blk, 0, stream, col, histT, e, NB, nba);
    hipLaunchKernelGGL(scan1_kernel,    dim3(nsb), dim3(SCAN_B), 0, stream, histT, histTs, bsum2, m);
    hipLaunchKernelGGL(scan2_kernel,    dim3(1),   dim3(SCAN_B), 0, stream, bsum2, nsb);
    hipLaunchKernelGGL(scanadd_kernel,  dim3((m + 255) / 256), blk, 0, stream, histTs, bsum2, m);
    hipLaunchKernelGGL(scatterA_kernel, dim3(nba), blk, 0, stream, row, col, histTs, tmp, e, NB, nba);
    hipLaunchKernelGGL(bucketC_kernel,  dim3(NB),  blk, 0, stream, tmp, histTs, row_ptr, pcnt, bktTot, dinv, n, e, NB, nba);
    hipLaunchKernelGGL(scanB_kernel,    dim3(1),   dim3(SCAN_B), 0, stream, bktTot, row_ptr, NB, n);
    hipLaunchKernelGGL(bucketD_kernel,  dim3(NB),  blk, 0, stream, tmp, histTs, bktTot, pcnt, row_ptr, pk, n, e, NB, nba);

    // ---- network ----
    hipLaunchKernelGGL(gemm1_kernel, gG, blk, 0, stream, x, W1, dinv, hs, n);
    hipLaunchKernelGGL(agg1_kernel,  gA, blk, 0, stream, hs, row_ptr, pk, dinv, b1, W2, hs2, n);
    hipLaunchKernelGGL(agg2_kernel,  gA, blk, 0, stream, hs2, row_ptr, pk, dinv, b2, Wl, bl, (float*)d_out, n);
}

// Round 8
// 168.915 us; speedup vs baseline: 2.3505x; 1.2183x over previous
//
#include <hip/hip_runtime.h>

#define IN_CH 128
#define HID 16
#define SHIFT 8            // bucket = dst >> 8  (256 nodes per bucket)
#define CA 16384           // edges per block in pass-A kernels
#define SCAN_B 512
#define MAXNB 512

// native clang vector types accepted by __builtin_nontemporal_*
typedef int vint4 __attribute__((ext_vector_type(4)));

// ============ pass A1: per-block per-bucket histogram ============

__global__ __launch_bounds__(256) void histA_kernel(
    const int* __restrict__ col, int* __restrict__ histT, int e, int NB, int nba) {
    __shared__ int hist[MAXNB];
    int j = blockIdx.x, t = threadIdx.x;
    for (int b = t; b < NB; b += 256) hist[b] = 0;
    __syncthreads();
    int e4 = e >> 2;
    const int4* c4p = (const int4*)col;
#pragma unroll
    for (int k = 0; k < CA / 1024; ++k) {
        int i4 = j * (CA / 4) + k * 256 + t;
        if (i4 < e4) {
            int4 c = c4p[i4];
            atomicAdd(&hist[c.x >> SHIFT], 1);
            atomicAdd(&hist[c.y >> SHIFT], 1);
            atomicAdd(&hist[c.z >> SHIFT], 1);
            atomicAdd(&hist[c.w >> SHIFT], 1);
        }
    }
    if (j == gridDim.x - 1) {
        for (int i = (e & ~3) + t; i < e; i += 256) atomicAdd(&hist[col[i] >> SHIFT], 1);
    }
    __syncthreads();
    for (int b = t; b < NB; b += 256) histT[b * nba + j] = hist[b];
}

// ============ 2-level exclusive scan of histT (m elements); bsum added inline by consumers ============

__global__ __launch_bounds__(SCAN_B) void scan1_kernel(
    const int* __restrict__ in, int* __restrict__ out, int* __restrict__ bsum, int m) {
    __shared__ int s[SCAN_B];
    int t = threadIdx.x;
    int i = blockIdx.x * SCAN_B + t;
    int v = (i < m) ? in[i] : 0;
    s[t] = v;
    __syncthreads();
    for (int off = 1; off < SCAN_B; off <<= 1) {
        int a = (t >= off) ? s[t - off] : 0;
        __syncthreads();
        s[t] += a;
        __syncthreads();
    }
    if (i < m) out[i] = s[t] - v;
    if (t == SCAN_B - 1) bsum[blockIdx.x] = s[t];
}

__global__ __launch_bounds__(SCAN_B) void scan2_kernel(int* __restrict__ bsum, int nb) {
    __shared__ int s[SCAN_B];
    int t = threadIdx.x;
    int v = (t < nb) ? bsum[t] : 0;
    s[t] = v;
    __syncthreads();
    for (int off = 1; off < SCAN_B; off <<= 1) {
        int a = (t >= off) ? s[t - off] : 0;
        __syncthreads();
        s[t] += a;
        __syncthreads();
    }
    if (t < nb) bsum[t] = s[t] - v;
}

// ============ pass A3: scatter edges into bucket runs in tmp ============

__global__ __launch_bounds__(256) void scatterA_kernel(
    const int* __restrict__ row, const int* __restrict__ col,
    const int* __restrict__ histTs, const int* __restrict__ bsum2,
    int* __restrict__ tmp, int e, int NB, int nba) {
    __shared__ int cur[MAXNB];
    int j = blockIdx.x, t = threadIdx.x;
    for (int b = t; b < NB; b += 256) {
        int idx = b * nba + j;
        cur[b] = histTs[idx] + bsum2[idx >> 9];
    }
    __syncthreads();
    int e4 = e >> 2;
    const int4* c4p = (const int4*)col;
    const int4* r4p = (const int4*)row;
#pragma unroll
    for (int k = 0; k < CA / 1024; ++k) {
        int i4 = j * (CA / 4) + k * 256 + t;
        if (i4 < e4) {
            int4 c = c4p[i4];
            int4 r = r4p[i4];
            int pos;
            pos = atomicAdd(&cur[c.x >> SHIFT], 1); tmp[pos] = (r.x << 8) | (c.x & 255);
            pos = atomicAdd(&cur[c.y >> SHIFT], 1); tmp[pos] = (r.y << 8) | (c.y & 255);
            pos = atomicAdd(&cur[c.z >> SHIFT], 1); tmp[pos] = (r.z << 8) | (c.z & 255);
            pos = atomicAdd(&cur[c.w >> SHIFT], 1); tmp[pos] = (r.w << 8) | (c.w & 255);
        }
    }
    if (j == gridDim.x - 1) {
        for (int i = (e & ~3) + t; i < e; i += 256) {
            int c = col[i], r = row[i];
            int pos = atomicAdd(&cur[c >> SHIFT], 1);
            tmp[pos] = (r << 8) | (c & 255);
        }
    }
}

// ============ pass C: per-bucket padded degree/offsets (NO global atomics) ============

__global__ __launch_bounds__(256) void bucketC_kernel(
    const int* __restrict__ tmp, const int* __restrict__ histTs, const int* __restrict__ bsum2,
    int* __restrict__ row_ptr, int* __restrict__ pcnt, int* __restrict__ bktTot,
    float* __restrict__ dinv, int n, int e, int NB, int nba) {
    __shared__ int hcnt[256];
    __shared__ int scn[256];
    int b = blockIdx.x, t = threadIdx.x;
    int i0 = b * nba, i1 = (b + 1) * nba;
    int bs = histTs[i0] + bsum2[i0 >> 9];
    int be = (b + 1 < NB) ? (histTs[i1] + bsum2[i1 >> 9]) : e;
    hcnt[t] = 0;
    __syncthreads();
    for (int i = bs + t; i < be; i += 256) atomicAdd(&hcnt[tmp[i] & 255], 1);
    __syncthreads();
    int cnt = hcnt[t];
    int pc = (cnt + 7) & ~7;
    scn[t] = pc;
    __syncthreads();
    for (int off = 1; off < 256; off <<= 1) {
        int a = (t >= off) ? scn[t - off] : 0;
        __syncthreads();
        scn[t] += a;
        __syncthreads();
    }
    int excl = scn[t] - pc;
    int node = (b << SHIFT) + t;
    if (node < n) {
        row_ptr[node] = excl;          // local offset for now
        pcnt[node] = pc;
        dinv[node] = rsqrtf((float)(cnt + 1));   // +1 self-loop
    }
    if (t == 255) bktTot[b] = scn[255];
    if (b == 0 && t == 0) dinv[n] = 0.0f;        // dummy row
}

// exclusive scan of bucket padded totals (NB <= 512), writes grand total to row_ptr[n]
__global__ __launch_bounds__(SCAN_B) void scanB_kernel(
    int* __restrict__ bktTot, int* __restrict__ row_ptr, int NB, int n) {
    __shared__ int s[SCAN_B];
    int t = threadIdx.x;
    int v = (t < NB) ? bktTot[t] : 0;
    s[t] = v;
    __syncthreads();
    for (int off = 1; off < SCAN_B; off <<= 1) {
        int a = (t >= off) ? s[t - off] : 0;
        __syncthreads();
        s[t] += a;
        __syncthreads();
    }
    if (t < NB) bktTot[t] = s[t] - v;
    if (t == SCAN_B - 1) row_ptr[n] = s[t];
}

// ============ pass D: finalize row_ptr, scatter into pk, pad tails with dummy n ============

__global__ __launch_bounds__(256) void bucketD_kernel(
    const int* __restrict__ tmp, const int* __restrict__ histTs, const int* __restrict__ bsum2,
    const int* __restrict__ bktTot, const int* __restrict__ pcnt,
    int* __restrict__ row_ptr, int* __restrict__ pk,
    int n, int e, int NB, int nba) {
    __shared__ int cur[256];
    int b = blockIdx.x, t = threadIdx.x;
    int i0 = b * nba, i1 = (b + 1) * nba;
    int bs = histTs[i0] + bsum2[i0 >> 9];
    int be = (b + 1 < NB) ? (histTs[i1] + bsum2[i1 >> 9]) : e;
    int node = (b << SHIFT) + t;
    int rp = 0, pc = 0;
    if (node < n) {
        rp = bktTot[b] + row_ptr[node];   // base + local offset
        pc = pcnt[node];
        row_ptr[node] = rp;
    }
    cur[t] = rp;
    __syncthreads();
    for (int i = bs + t; i < be; i += 256) {
        int u = tmp[i];
        int pos = atomicAdd(&cur[u & 255], 1);
        pk[pos] = u >> 8;
    }
    __syncthreads();
    int pe = rp + pc;
    for (int p = cur[t]; p < pe; ++p) pk[p] = n;   // <=7 dummy pads per node
}

// ============ layer 1 dense: hs = dinv * (x @ W1), 4 lanes/row, x in registers ============
// W1 staged in LDS with k-swizzle kp=(k&31)*4+(k>>5) so the 4 sub-lanes' b128 reads
// hit different bank quads (2-way aliasing = free). Lane sub covers k in [sub*32, sub*32+32).

__global__ __launch_bounds__(256) void gemm1_kernel(
    const float* __restrict__ x, const float* __restrict__ W1,
    const float* __restrict__ dinv, float* __restrict__ hs, int n) {
    __shared__ float4 swl[512];   // swl[kp*4 + i] = W1[k][4i..4i+3]
    int t = threadIdx.x;
#pragma unroll
    for (int i = t; i < 512; i += 256) {
        float4 v = ((const float4*)W1)[i];
        int k = i >> 2, q = i & 3;
        int kp = ((k & 31) << 2) | (k >> 5);
        swl[kp * 4 + q] = v;
    }
    __syncthreads();
    int gid = blockIdx.x * 256 + t;
    int r = gid >> 2;        // node row
    int sub = gid & 3;       // k-quarter
    if (r > n) return;
    float4 xv[8];
    if (r < n) {
        const float4* xp = (const float4*)(x + (size_t)r * IN_CH + sub * 32);
#pragma unroll
        for (int j = 0; j < 8; ++j) xv[j] = xp[j];
    } else {
#pragma unroll
        for (int j = 0; j < 8; ++j) xv[j] = make_float4(0.f, 0.f, 0.f, 0.f);
    }
    float acc[16];
#pragma unroll
    for (int c = 0; c < 16; ++c) acc[c] = 0.f;
#pragma unroll
    for (int j = 0; j < 8; ++j) {
#pragma unroll
        for (int q = 0; q < 4; ++q) {
            int jq = j * 4 + q;
            float xs = (q == 0) ? xv[j].x : (q == 1) ? xv[j].y : (q == 2) ? xv[j].z : xv[j].w;
            const float4* wp = &swl[(jq * 4 + sub) * 4];
            float4 w0 = wp[0], w1 = wp[1], w2 = wp[2], w3 = wp[3];
            acc[0]  = fmaf(xs, w0.x, acc[0]);
            acc[1]  = fmaf(xs, w0.y, acc[1]);
            acc[2]  = fmaf(xs, w0.z, acc[2]);
            acc[3]  = fmaf(xs, w0.w, acc[3]);
            acc[4]  = fmaf(xs, w1.x, acc[4]);
            acc[5]  = fmaf(xs, w1.y, acc[5]);
            acc[6]  = fmaf(xs, w1.z, acc[6]);
            acc[7]  = fmaf(xs, w1.w, acc[7]);
            acc[8]  = fmaf(xs, w2.x, acc[8]);
            acc[9]  = fmaf(xs, w2.y, acc[9]);
            acc[10] = fmaf(xs, w2.z, acc[10]);
            acc[11] = fmaf(xs, w2.w, acc[11]);
            acc[12] = fmaf(xs, w3.x, acc[12]);
            acc[13] = fmaf(xs, w3.y, acc[13]);
            acc[14] = fmaf(xs, w3.z, acc[14]);
            acc[15] = fmaf(xs, w3.w, acc[15]);
        }
    }
    // reduce the 4 k-quarters within each 4-lane group
#pragma unroll
    for (int c = 0; c < 16; ++c) {
        acc[c] += __shfl_xor(acc[c], 1);
        acc[c] += __shfl_xor(acc[c], 2);
    }
    float dg = dinv[r];      // dinv[n] == 0 -> dummy row zeroed
    float4 o;
    o.x = dg * acc[sub * 4 + 0];
    o.y = dg * acc[sub * 4 + 1];
    o.z = dg * acc[sub * 4 + 2];
    o.w = dg * acc[sub * 4 + 3];
    ((float4*)hs)[(size_t)r * 4 + sub] = o;
}

// ============ aggregation, full 64B rows, padded unroll-8, fused epilogues ============

__global__ __launch_bounds__(256) void agg1_kernel(
    const float* __restrict__ hs, const int* __restrict__ row_ptr,
    const int* __restrict__ pk, const float* __restrict__ dinv,
    const float* __restrict__ b1, const float* __restrict__ W2,
    float* __restrict__ hs2, int n) {
    int t = threadIdx.x;
    int node = blockIdx.x * 64 + (t >> 2);
    int sub = t & 3;
    if (node >= n) return;   // whole 4-lane group exits together
    const float4* h4 = (const float4*)hs;
    float4 self = h4[(size_t)node * 4 + sub];
    float cx = self.x, cy = self.y, cz = self.z, cw = self.w;
    int beg = __builtin_nontemporal_load(row_ptr + node);
    int end = __builtin_nontemporal_load(row_ptr + node + 1);
    for (int j = beg; j < end; j += 8) {
        vint4 p0 = __builtin_nontemporal_load((const vint4*)(pk + j));
        vint4 p1 = __builtin_nontemporal_load((const vint4*)(pk + j + 4));
        float4 v0 = h4[(size_t)p0.x * 4 + sub];
        float4 v1 = h4[(size_t)p0.y * 4 + sub];
        float4 v2 = h4[(size_t)p0.z * 4 + sub];
        float4 v3 = h4[(size_t)p0.w * 4 + sub];
        float4 v4 = h4[(size_t)p1.x * 4 + sub];
        float4 v5 = h4[(size_t)p1.y * 4 + sub];
        float4 v6 = h4[(size_t)p1.z * 4 + sub];
        float4 v7 = h4[(size_t)p1.w * 4 + sub];
        cx += ((v0.x + v1.x) + (v2.x + v3.x)) + ((v4.x + v5.x) + (v6.x + v7.x));
        cy += ((v0.y + v1.y) + (v2.y + v3.y)) + ((v4.y + v5.y) + (v6.y + v7.y));
        cz += ((v0.z + v1.z) + (v2.z + v3.z)) + ((v4.z + v5.z) + (v6.z + v7.z));
        cw += ((v0.w + v1.w) + (v2.w + v3.w)) + ((v4.w + v5.w) + (v6.w + v7.w));
    }
    float dg = dinv[node];
    float4 b1v = *(const float4*)(b1 + (sub << 2));
    float ax = fmaxf(fmaf(dg, cx, b1v.x), 0.f);
    float ay = fmaxf(fmaf(dg, cy, b1v.y), 0.f);
    float az = fmaxf(fmaf(dg, cz, b1v.z), 0.f);
    float aw = fmaxf(fmaf(dg, cw, b1v.w), 0.f);
    float ox = 0.f, oy = 0.f, oz = 0.f, ow = 0.f;
#pragma unroll
    for (int r = 0; r < 4; ++r) {
        float fx = __shfl_xor(ax, r);
        float fy = __shfl_xor(ay, r);
        float fz = __shfl_xor(az, r);
        float fw = __shfl_xor(aw, r);
        int kb = (sub ^ r) << 2;                       // input-channel block held by partner lane
        const float* wp = W2 + kb * HID + (sub << 2);  // rows kb..kb+3, cols 4*sub..
        float4 w0 = *(const float4*)(wp);
        float4 w1 = *(const float4*)(wp + HID);
        float4 w2 = *(const float4*)(wp + 2 * HID);
        float4 w3 = *(const float4*)(wp + 3 * HID);
        ox += fx * w0.x + fy * w1.x + fz * w2.x + fw * w3.x;
        oy += fx * w0.y + fy * w1.y + fz * w2.y + fw * w3.y;
        oz += fx * w0.z + fy * w1.z + fz * w2.z + fw * w3.z;
        ow += fx * w0.w + fy * w1.w + fz * w2.w + fw * w3.w;
    }
    float4 o; o.x = dg * ox; o.y = dg * oy; o.z = dg * oz; o.w = dg * ow;
    ((float4*)hs2)[(size_t)node * 4 + sub] = o;
}

__global__ __launch_bounds__(256) void agg2_kernel(
    const float* __restrict__ hs2, const int* __restrict__ row_ptr,
    const int* __restrict__ pk, const float* __restrict__ dinv,
    const float* __restrict__ b2, const float* __restrict__ Wl,
    const float* __restrict__ bl, float* __restrict__ out, int n) {
    int t = threadIdx.x;
    int node = blockIdx.x * 64 + (t >> 2);
    int sub = t & 3;
    if (node >= n) return;
    const float4* h4 = (const float4*)hs2;
    float4 self = h4[(size_t)node * 4 + sub];
    float cx = self.x, cy = self.y, cz = self.z, cw = self.w;
    int beg = __builtin_nontemporal_load(row_ptr + node);
    int end = __builtin_nontemporal_load(row_ptr + node + 1);
    for (int j = beg; j < end; j += 8) {
        vint4 p0 = __builtin_nontemporal_load((const vint4*)(pk + j));
        vint4 p1 = __builtin_nontemporal_load((const vint4*)(pk + j + 4));
        float4 v0 = h4[(size_t)p0.x * 4 + sub];
        float4 v1 = h4[(size_t)p0.y * 4 + sub];
        float4 v2 = h4[(size_t)p0.z * 4 + sub];
        float4 v3 = h4[(size_t)p0.w * 4 + sub];
        float4 v4 = h4[(size_t)p1.x * 4 + sub];
        float4 v5 = h4[(size_t)p1.y * 4 + sub];
        float4 v6 = h4[(size_t)p1.z * 4 + sub];
        float4 v7 = h4[(size_t)p1.w * 4 + sub];
        cx += ((v0.x + v1.x) + (v2.x + v3.x)) + ((v4.x + v5.x) + (v6.x + v7.x));
        cy += ((v0.y + v1.y) + (v2.y + v3.y)) + ((v4.y + v5.y) + (v6.y + v7.y));
        cz += ((v0.z + v1.z) + (v2.z + v3.z)) + ((v4.z + v5.z) + (v6.z + v7.z));
        cw += ((v0.w + v1.w) + (v2.w + v3.w)) + ((v4.w + v5.w) + (v6.w + v7.w));
    }
    float dg = dinv[node];
    float4 b2v = *(const float4*)(b2 + (sub << 2));
    float4 wlv = *(const float4*)(Wl + (sub << 2));
    float p = fmaxf(fmaf(dg, cx, b2v.x), 0.f) * wlv.x
            + fmaxf(fmaf(dg, cy, b2v.y), 0.f) * wlv.y
            + fmaxf(fmaf(dg, cz, b2v.z), 0.f) * wlv.z
            + fmaxf(fmaf(dg, cw, b2v.w), 0.f) * wlv.w;
    p += __shfl_xor(p, 1);
    p += __shfl_xor(p, 2);
    if (sub == 0) out[node] = p + bl[0];
}

extern "C" void kernel_launch(void* const* d_in, const int* in_sizes, int n_in,
                              void* d_out, int out_size, void* d_ws, size_t ws_size,
                              hipStream_t stream) {
    const float* x  = (const float*)d_in[0];
    const int*   ei = (const int*)d_in[1];
    const float* W1 = (const float*)d_in[2];
    const float* b1 = (const float*)d_in[3];
    const float* W2 = (const float*)d_in[4];
    const float* b2 = (const float*)d_in[5];
    const float* Wl = (const float*)d_in[6];
    const float* bl = (const float*)d_in[7];

    int n = in_sizes[0] / IN_CH;
    int e = in_sizes[1] / 2;
    const int* row = ei;        // sources
    const int* col = ei + e;    // targets

    int NB  = (n + 255) >> SHIFT;            // 391 (<=512)
    int nba = (e + CA - 1) / CA;             // 196
    int m   = NB * nba;
    int nsb = (m + SCAN_B - 1) / SCAN_B;     // 150 (<=512)

    char* ws = (char*)d_ws;
    size_t off = 0;
    auto alloc = [&](size_t bytes) -> void* {
        void* p = ws + off;
        off = (off + bytes + 255) & ~(size_t)255;
        return p;
    };

    size_t tabf = (size_t)(n + 1) * HID;     // floats per table (incl. dummy row)

    int*   histT   = (int*)alloc((size_t)m * 4);
    int*   histTs  = (int*)alloc((size_t)m * 4);
    int*   bsum2   = (int*)alloc((size_t)nsb * 4);
    int*   row_ptr = (int*)alloc(((size_t)n + 1) * 4);
    int*   pcnt    = (int*)alloc((size_t)n * 4);
    int*   bktTot  = (int*)alloc((size_t)NB * 4);
    float* dinv    = (float*)alloc(((size_t)n + 1) * 4);
    int*   pk      = (int*)alloc(((size_t)e + 8 * (size_t)n + 64) * 4);
    // overlay: tmp (edge staging) dies before the two tables are born
    size_t region = (size_t)e * 4;
    size_t tables = 2 * tabf * 4;
    char*  R      = (char*)alloc(region > tables ? region : tables);
    int*   tmp    = (int*)R;
    float* hs     = (float*)R;
    float* hs2    = hs + tabf;

    dim3 blk(256);
    dim3 gG((4 * (n + 1) + 255) / 256);
    dim3 gA((n + 63) / 64);

    // ---- CSR build (padded, dst-sorted, zero global atomics) ----
    hipLaunchKernelGGL(histA_kernel,    dim3(nba), blk, 0, stream, col, histT, e, NB, nba);
    hipLaunchKernelGGL(scan1_kernel,    dim3(nsb), dim3(SCAN_B), 0, stream, histT, histTs, bsum2, m);
    hipLaunchKernelGGL(scan2_kernel,    dim3(1),   dim3(SCAN_B), 0, stream, bsum2, nsb);
    hipLaunchKernelGGL(scatterA_kernel, dim3(nba), blk, 0, stream, row, col, histTs, bsum2, tmp, e, NB, nba);
    hipLaunchKernelGGL(bucketC_kernel,  dim3(NB),  blk, 0, stream, tmp, histTs, bsum2, row_ptr, pcnt, bktTot, dinv, n, e, NB, nba);
    hipLaunchKernelGGL(scanB_kernel,    dim3(1),   dim3(SCAN_B), 0, stream, bktTot, row_ptr, NB, n);
    hipLaunchKernelGGL(bucketD_kernel,  dim3(NB),  blk, 0, stream, tmp, histTs, bsum2, bktTot, pcnt, row_ptr, pk, n, e, NB, nba);

    // ---- network ----
    hipLaunchKernelGGL(gemm1_kernel, gG, blk, 0, stream, x, W1, dinv, hs, n);
    hipLaunchKernelGGL(agg1_kernel,  gA, blk, 0, stream, hs, row_ptr, pk, dinv, b1, W2, hs2, n);
    hipLaunchKernelGGL(agg2_kernel,  gA, blk, 0, stream, hs2, row_ptr, pk, dinv, b2, Wl, bl, (float*)d_out, n);
}

// Round 9
// 154.746 us; speedup vs baseline: 2.5657x; 1.0916x over previous
//
#include <hip/hip_runtime.h>

#define IN_CH 128
#define HID 16
#define SHIFT 8            // bucket = dst >> 8  (256 nodes per bucket)
#define CA 16384           // edges per block in pass-A kernels
#define SCAN_B 512
#define MAXNB 512

// native clang vector types accepted by __builtin_nontemporal_*
typedef int vint4 __attribute__((ext_vector_type(4)));

// ============ pass A1: per-block per-bucket histogram ============

__global__ __launch_bounds__(256) void histA_kernel(
    const int* __restrict__ col, int* __restrict__ histT, int e, int NB, int nba) {
    __shared__ int hist[MAXNB];
    int j = blockIdx.x, t = threadIdx.x;
    for (int b = t; b < NB; b += 256) hist[b] = 0;
    __syncthreads();
    int e4 = e >> 2;
    const int4* c4p = (const int4*)col;
#pragma unroll
    for (int k = 0; k < CA / 1024; ++k) {
        int i4 = j * (CA / 4) + k * 256 + t;
        if (i4 < e4) {
            int4 c = c4p[i4];
            atomicAdd(&hist[c.x >> SHIFT], 1);
            atomicAdd(&hist[c.y >> SHIFT], 1);
            atomicAdd(&hist[c.z >> SHIFT], 1);
            atomicAdd(&hist[c.w >> SHIFT], 1);
        }
    }
    if (j == gridDim.x - 1) {
        for (int i = (e & ~3) + t; i < e; i += 256) atomicAdd(&hist[col[i] >> SHIFT], 1);
    }
    __syncthreads();
    for (int b = t; b < NB; b += 256) histT[b * nba + j] = hist[b];
}

// ============ 2-level exclusive scan of histT (m elements); bsum added inline by consumers ============

__global__ __launch_bounds__(SCAN_B) void scan1_kernel(
    const int* __restrict__ in, int* __restrict__ out, int* __restrict__ bsum, int m) {
    __shared__ int s[SCAN_B];
    int t = threadIdx.x;
    int i = blockIdx.x * SCAN_B + t;
    int v = (i < m) ? in[i] : 0;
    s[t] = v;
    __syncthreads();
    for (int off = 1; off < SCAN_B; off <<= 1) {
        int a = (t >= off) ? s[t - off] : 0;
        __syncthreads();
        s[t] += a;
        __syncthreads();
    }
    if (i < m) out[i] = s[t] - v;
    if (t == SCAN_B - 1) bsum[blockIdx.x] = s[t];
}

__global__ __launch_bounds__(SCAN_B) void scan2_kernel(int* __restrict__ bsum, int nb) {
    __shared__ int s[SCAN_B];
    int t = threadIdx.x;
    int v = (t < nb) ? bsum[t] : 0;
    s[t] = v;
    __syncthreads();
    for (int off = 1; off < SCAN_B; off <<= 1) {
        int a = (t >= off) ? s[t - off] : 0;
        __syncthreads();
        s[t] += a;
        __syncthreads();
    }
    if (t < nb) bsum[t] = s[t] - v;
}

// ============ pass A3: scatter edges into bucket runs in tmp ============

__global__ __launch_bounds__(256) void scatterA_kernel(
    const int* __restrict__ row, const int* __restrict__ col,
    const int* __restrict__ histTs, const int* __restrict__ bsum2,
    int* __restrict__ tmp, int e, int NB, int nba) {
    __shared__ int cur[MAXNB];
    int j = blockIdx.x, t = threadIdx.x;
    for (int b = t; b < NB; b += 256) {
        int idx = b * nba + j;
        cur[b] = histTs[idx] + bsum2[idx >> 9];
    }
    __syncthreads();
    int e4 = e >> 2;
    const int4* c4p = (const int4*)col;
    const int4* r4p = (const int4*)row;
#pragma unroll
    for (int k = 0; k < CA / 1024; ++k) {
        int i4 = j * (CA / 4) + k * 256 + t;
        if (i4 < e4) {
            int4 c = c4p[i4];
            int4 r = r4p[i4];
            int pos;
            pos = atomicAdd(&cur[c.x >> SHIFT], 1); tmp[pos] = (r.x << 8) | (c.x & 255);
            pos = atomicAdd(&cur[c.y >> SHIFT], 1); tmp[pos] = (r.y << 8) | (c.y & 255);
            pos = atomicAdd(&cur[c.z >> SHIFT], 1); tmp[pos] = (r.z << 8) | (c.z & 255);
            pos = atomicAdd(&cur[c.w >> SHIFT], 1); tmp[pos] = (r.w << 8) | (c.w & 255);
        }
    }
    if (j == gridDim.x - 1) {
        for (int i = (e & ~3) + t; i < e; i += 256) {
            int c = col[i], r = row[i];
            int pos = atomicAdd(&cur[c >> SHIFT], 1);
            tmp[pos] = (r << 8) | (c & 255);
        }
    }
}

// ============ pass C: per-bucket padded degree/offsets (NO global atomics) ============

__global__ __launch_bounds__(256) void bucketC_kernel(
    const int* __restrict__ tmp, const int* __restrict__ histTs, const int* __restrict__ bsum2,
    int* __restrict__ row_ptr, int* __restrict__ pcnt, int* __restrict__ bktTot,
    float* __restrict__ dinv, int n, int e, int NB, int nba) {
    __shared__ int hcnt[256];
    __shared__ int scn[256];
    int b = blockIdx.x, t = threadIdx.x;
    int i0 = b * nba, i1 = (b + 1) * nba;
    int bs = histTs[i0] + bsum2[i0 >> 9];
    int be = (b + 1 < NB) ? (histTs[i1] + bsum2[i1 >> 9]) : e;
    hcnt[t] = 0;
    __syncthreads();
    for (int i = bs + t; i < be; i += 256) atomicAdd(&hcnt[tmp[i] & 255], 1);
    __syncthreads();
    int cnt = hcnt[t];
    int pc = (cnt + 7) & ~7;
    scn[t] = pc;
    __syncthreads();
    for (int off = 1; off < 256; off <<= 1) {
        int a = (t >= off) ? scn[t - off] : 0;
        __syncthreads();
        scn[t] += a;
        __syncthreads();
    }
    int excl = scn[t] - pc;
    int node = (b << SHIFT) + t;
    if (node < n) {
        row_ptr[node] = excl;          // local offset for now
        pcnt[node] = pc;
        dinv[node] = rsqrtf((float)(cnt + 1));   // +1 self-loop
    }
    if (t == 255) bktTot[b] = scn[255];
    if (b == 0 && t == 0) dinv[n] = 0.0f;        // dummy row
}

// exclusive scan of bucket padded totals (NB <= 512), writes grand total to row_ptr[n]
__global__ __launch_bounds__(SCAN_B) void scanB_kernel(
    int* __restrict__ bktTot, int* __restrict__ row_ptr, int NB, int n) {
    __shared__ int s[SCAN_B];
    int t = threadIdx.x;
    int v = (t < NB) ? bktTot[t] : 0;
    s[t] = v;
    __syncthreads();
    for (int off = 1; off < SCAN_B; off <<= 1) {
        int a = (t >= off) ? s[t - off] : 0;
        __syncthreads();
        s[t] += a;
        __syncthreads();
    }
    if (t < NB) bktTot[t] = s[t] - v;
    if (t == SCAN_B - 1) row_ptr[n] = s[t];
}

// ============ pass D: finalize row_ptr, scatter into pk, pad tails with dummy n ============

__global__ __launch_bounds__(256) void bucketD_kernel(
    const int* __restrict__ tmp, const int* __restrict__ histTs, const int* __restrict__ bsum2,
    const int* __restrict__ bktTot, const int* __restrict__ pcnt,
    int* __restrict__ row_ptr, int* __restrict__ pk,
    int n, int e, int NB, int nba) {
    __shared__ int cur[256];
    int b = blockIdx.x, t = threadIdx.x;
    int i0 = b * nba, i1 = (b + 1) * nba;
    int bs = histTs[i0] + bsum2[i0 >> 9];
    int be = (b + 1 < NB) ? (histTs[i1] + bsum2[i1 >> 9]) : e;
    int node = (b << SHIFT) + t;
    int rp = 0, pc = 0;
    if (node < n) {
        rp = bktTot[b] + row_ptr[node];   // base + local offset
        pc = pcnt[node];
        row_ptr[node] = rp;
    }
    cur[t] = rp;
    __syncthreads();
    for (int i = bs + t; i < be; i += 256) {
        int u = tmp[i];
        int pos = atomicAdd(&cur[u & 255], 1);
        pk[pos] = u >> 8;
    }
    __syncthreads();
    int pe = rp + pc;
    for (int p = cur[t]; p < pe; ++p) pk[p] = n;   // <=7 dummy pads per node
}

// ============ layer 1 dense: hs = dinv * (x @ W1), 4 lanes/row, x in registers ============

__global__ __launch_bounds__(256) void gemm1_kernel(
    const float* __restrict__ x, const float* __restrict__ W1,
    const float* __restrict__ dinv, float* __restrict__ hs, int n) {
    __shared__ float4 swl[512];   // swl[kp*4 + i] = W1[k][4i..4i+3]
    int t = threadIdx.x;
#pragma unroll
    for (int i = t; i < 512; i += 256) {
        float4 v = ((const float4*)W1)[i];
        int k = i >> 2, q = i & 3;
        int kp = ((k & 31) << 2) | (k >> 5);
        swl[kp * 4 + q] = v;
    }
    __syncthreads();
    int gid = blockIdx.x * 256 + t;
    int r = gid >> 2;        // node row
    int sub = gid & 3;       // k-quarter
    if (r > n) return;
    float4 xv[8];
    if (r < n) {
        const float4* xp = (const float4*)(x + (size_t)r * IN_CH + sub * 32);
#pragma unroll
        for (int j = 0; j < 8; ++j) xv[j] = xp[j];
    } else {
#pragma unroll
        for (int j = 0; j < 8; ++j) xv[j] = make_float4(0.f, 0.f, 0.f, 0.f);
    }
    float acc[16];
#pragma unroll
    for (int c = 0; c < 16; ++c) acc[c] = 0.f;
#pragma unroll
    for (int j = 0; j < 8; ++j) {
#pragma unroll
        for (int q = 0; q < 4; ++q) {
            int jq = j * 4 + q;
            float xs = (q == 0) ? xv[j].x : (q == 1) ? xv[j].y : (q == 2) ? xv[j].z : xv[j].w;
            const float4* wp = &swl[(jq * 4 + sub) * 4];
            float4 w0 = wp[0], w1 = wp[1], w2 = wp[2], w3 = wp[3];
            acc[0]  = fmaf(xs, w0.x, acc[0]);
            acc[1]  = fmaf(xs, w0.y, acc[1]);
            acc[2]  = fmaf(xs, w0.z, acc[2]);
            acc[3]  = fmaf(xs, w0.w, acc[3]);
            acc[4]  = fmaf(xs, w1.x, acc[4]);
            acc[5]  = fmaf(xs, w1.y, acc[5]);
            acc[6]  = fmaf(xs, w1.z, acc[6]);
            acc[7]  = fmaf(xs, w1.w, acc[7]);
            acc[8]  = fmaf(xs, w2.x, acc[8]);
            acc[9]  = fmaf(xs, w2.y, acc[9]);
            acc[10] = fmaf(xs, w2.z, acc[10]);
            acc[11] = fmaf(xs, w2.w, acc[11]);
            acc[12] = fmaf(xs, w3.x, acc[12]);
            acc[13] = fmaf(xs, w3.y, acc[13]);
            acc[14] = fmaf(xs, w3.z, acc[14]);
            acc[15] = fmaf(xs, w3.w, acc[15]);
        }
    }
#pragma unroll
    for (int c = 0; c < 16; ++c) {
        acc[c] += __shfl_xor(acc[c], 1);
        acc[c] += __shfl_xor(acc[c], 2);
    }
    float dg = dinv[r];      // dinv[n] == 0 -> dummy row zeroed
    float4 o;
    o.x = dg * acc[sub * 4 + 0];
    o.y = dg * acc[sub * 4 + 1];
    o.z = dg * acc[sub * 4 + 2];
    o.w = dg * acc[sub * 4 + 3];
    ((float4*)hs)[(size_t)r * 4 + sub] = o;
}

// ============ aggregation, 8 lanes/node (2 quads split the list), pk software-pipelined ============
// quad qd walks blocks beg+qd*8, step 16; cross-quad combine via shfl_xor(...,4) BEFORE epilogue.

#define AGG_GATHER_LOOP                                                          \
    int beg = __builtin_nontemporal_load(row_ptr + node);                        \
    int end = __builtin_nontemporal_load(row_ptr + node + 1);                    \
    int j = beg + (qd << 3);                                                     \
    vint4 p0, p1;                                                                \
    if (j < end) {                                                               \
        p0 = __builtin_nontemporal_load((const vint4*)(pk + j));                 \
        p1 = __builtin_nontemporal_load((const vint4*)(pk + j + 4));             \
    }                                                                            \
    while (j < end) {                                                            \
        int jn = j + 16;                                                         \
        vint4 q0, q1;                                                            \
        if (jn < end) {                                                          \
            q0 = __builtin_nontemporal_load((const vint4*)(pk + jn));            \
            q1 = __builtin_nontemporal_load((const vint4*)(pk + jn + 4));        \
        }                                                                        \
        float4 v0 = h4[(size_t)p0.x * 4 + sub];                                  \
        float4 v1 = h4[(size_t)p0.y * 4 + sub];                                  \
        float4 v2 = h4[(size_t)p0.z * 4 + sub];                                  \
        float4 v3 = h4[(size_t)p0.w * 4 + sub];                                  \
        float4 v4 = h4[(size_t)p1.x * 4 + sub];                                  \
        float4 v5 = h4[(size_t)p1.y * 4 + sub];                                  \
        float4 v6 = h4[(size_t)p1.z * 4 + sub];                                  \
        float4 v7 = h4[(size_t)p1.w * 4 + sub];                                  \
        cx += ((v0.x + v1.x) + (v2.x + v3.x)) + ((v4.x + v5.x) + (v6.x + v7.x)); \
        cy += ((v0.y + v1.y) + (v2.y + v3.y)) + ((v4.y + v5.y) + (v6.y + v7.y)); \
        cz += ((v0.z + v1.z) + (v2.z + v3.z)) + ((v4.z + v5.z) + (v6.z + v7.z)); \
        cw += ((v0.w + v1.w) + (v2.w + v3.w)) + ((v4.w + v5.w) + (v6.w + v7.w)); \
        p0 = q0; p1 = q1; j = jn;                                                \
    }                                                                            \
    cx += __shfl_xor(cx, 4);                                                     \
    cy += __shfl_xor(cy, 4);                                                     \
    cz += __shfl_xor(cz, 4);                                                     \
    cw += __shfl_xor(cw, 4);

__global__ __launch_bounds__(256) void agg1_kernel(
    const float* __restrict__ hs, const int* __restrict__ row_ptr,
    const int* __restrict__ pk, const float* __restrict__ dinv,
    const float* __restrict__ b1, const float* __restrict__ W2,
    float* __restrict__ hs2, int n) {
    int t = threadIdx.x;
    int node = blockIdx.x * 32 + (t >> 3);
    int sub = t & 3;          // channel quarter
    int qd  = (t >> 2) & 1;   // list half
    if (node >= n) return;    // whole 8-lane group exits together
    const float4* h4 = (const float4*)hs;
    float4 self = h4[(size_t)node * 4 + sub];
    // quad 1 must not double-count the self term
    float cx = qd ? 0.f : self.x, cy = qd ? 0.f : self.y;
    float cz = qd ? 0.f : self.z, cw = qd ? 0.f : self.w;
    AGG_GATHER_LOOP
    float dg = dinv[node];
    float4 b1v = *(const float4*)(b1 + (sub << 2));
    float ax = fmaxf(fmaf(dg, cx, b1v.x), 0.f);
    float ay = fmaxf(fmaf(dg, cy, b1v.y), 0.f);
    float az = fmaxf(fmaf(dg, cz, b1v.z), 0.f);
    float aw = fmaxf(fmaf(dg, cw, b1v.w), 0.f);
    float ox = 0.f, oy = 0.f, oz = 0.f, ow = 0.f;
#pragma unroll
    for (int r = 0; r < 4; ++r) {
        float fx = __shfl_xor(ax, r);
        float fy = __shfl_xor(ay, r);
        float fz = __shfl_xor(az, r);
        float fw = __shfl_xor(aw, r);
        int kb = (sub ^ r) << 2;
        const float* wp = W2 + kb * HID + (sub << 2);
        float4 w0 = *(const float4*)(wp);
        float4 w1 = *(const float4*)(wp + HID);
        float4 w2 = *(const float4*)(wp + 2 * HID);
        float4 w3 = *(const float4*)(wp + 3 * HID);
        ox += fx * w0.x + fy * w1.x + fz * w2.x + fw * w3.x;
        oy += fx * w0.y + fy * w1.y + fz * w2.y + fw * w3.y;
        oz += fx * w0.z + fy * w1.z + fz * w2.z + fw * w3.z;
        ow += fx * w0.w + fy * w1.w + fz * w2.w + fw * w3.w;
    }
    if (qd == 0) {
        float4 o; o.x = dg * ox; o.y = dg * oy; o.z = dg * oz; o.w = dg * ow;
        ((float4*)hs2)[(size_t)node * 4 + sub] = o;
    }
}

__global__ __launch_bounds__(256) void agg2_kernel(
    const float* __restrict__ hs2, const int* __restrict__ row_ptr,
    const int* __restrict__ pk, const float* __restrict__ dinv,
    const float* __restrict__ b2, const float* __restrict__ Wl,
    const float* __restrict__ bl, float* __restrict__ out, int n) {
    int t = threadIdx.x;
    int node = blockIdx.x * 32 + (t >> 3);
    int sub = t & 3;
    int qd  = (t >> 2) & 1;
    if (node >= n) return;
    const float4* h4 = (const float4*)hs2;
    float4 self = h4[(size_t)node * 4 + sub];
    float cx = qd ? 0.f : self.x, cy = qd ? 0.f : self.y;
    float cz = qd ? 0.f : self.z, cw = qd ? 0.f : self.w;
    AGG_GATHER_LOOP
    float dg = dinv[node];
    float4 b2v = *(const float4*)(b2 + (sub << 2));
    float4 wlv = *(const float4*)(Wl + (sub << 2));
    float p = fmaxf(fmaf(dg, cx, b2v.x), 0.f) * wlv.x
            + fmaxf(fmaf(dg, cy, b2v.y), 0.f) * wlv.y
            + fmaxf(fmaf(dg, cz, b2v.z), 0.f) * wlv.z
            + fmaxf(fmaf(dg, cw, b2v.w), 0.f) * wlv.w;
    p += __shfl_xor(p, 1);
    p += __shfl_xor(p, 2);
    if ((t & 7) == 0) out[node] = p + bl[0];
}

extern "C" void kernel_launch(void* const* d_in, const int* in_sizes, int n_in,
                              void* d_out, int out_size, void* d_ws, size_t ws_size,
                              hipStream_t stream) {
    const float* x  = (const float*)d_in[0];
    const int*   ei = (const int*)d_in[1];
    const float* W1 = (const float*)d_in[2];
    const float* b1 = (const float*)d_in[3];
    const float* W2 = (const float*)d_in[4];
    const float* b2 = (const float*)d_in[5];
    const float* Wl = (const float*)d_in[6];
    const float* bl = (const float*)d_in[7];

    int n = in_sizes[0] / IN_CH;
    int e = in_sizes[1] / 2;
    const int* row = ei;        // sources
    const int* col = ei + e;    // targets

    int NB  = (n + 255) >> SHIFT;            // 391 (<=512)
    int nba = (e + CA - 1) / CA;             // 196
    int m   = NB * nba;
    int nsb = (m + SCAN_B - 1) / SCAN_B;     // 150 (<=512)

    char* ws = (char*)d_ws;
    size_t off = 0;
    auto alloc = [&](size_t bytes) -> void* {
        void* p = ws + off;
        off = (off + bytes + 255) & ~(size_t)255;
        return p;
    };

    size_t tabf = (size_t)(n + 1) * HID;     // floats per table (incl. dummy row)

    int*   histT   = (int*)alloc((size_t)m * 4);
    int*   histTs  = (int*)alloc((size_t)m * 4);
    int*   bsum2   = (int*)alloc((size_t)nsb * 4);
    int*   row_ptr = (int*)alloc(((size_t)n + 1) * 4);
    int*   pcnt    = (int*)alloc((size_t)n * 4);
    int*   bktTot  = (int*)alloc((size_t)NB * 4);
    float* dinv    = (float*)alloc(((size_t)n + 1) * 4);
    int*   pk      = (int*)alloc(((size_t)e + 8 * (size_t)n + 64) * 4);
    // overlay: tmp (edge staging) dies before the two tables are born
    size_t region = (size_t)e * 4;
    size_t tables = 2 * tabf * 4;
    char*  R      = (char*)alloc(region > tables ? region : tables);
    int*   tmp    = (int*)R;
    float* hs     = (float*)R;
    float* hs2    = hs + tabf;

    dim3 blk(256);
    dim3 gG((4 * (n + 1) + 255) / 256);
    dim3 gA((8 * n + 255) / 256);            // 8 lanes per node

    // ---- CSR build (padded, dst-sorted, zero global atomics) ----
    hipLaunchKernelGGL(histA_kernel,    dim3(nba), blk, 0, stream, col, histT, e, NB, nba);
    hipLaunchKernelGGL(scan1_kernel,    dim3(nsb), dim3(SCAN_B), 0, stream, histT, histTs, bsum2, m);
    hipLaunchKernelGGL(scan2_kernel,    dim3(1),   dim3(SCAN_B), 0, stream, bsum2, nsb);
    hipLaunchKernelGGL(scatterA_kernel, dim3(nba), blk, 0, stream, row, col, histTs, bsum2, tmp, e, NB, nba);
    hipLaunchKernelGGL(bucketC_kernel,  dim3(NB),  blk, 0, stream, tmp, histTs, bsum2, row_ptr, pcnt, bktTot, dinv, n, e, NB, nba);
    hipLaunchKernelGGL(scanB_kernel,    dim3(1),   dim3(SCAN_B), 0, stream, bktTot, row_ptr, NB, n);
    hipLaunchKernelGGL(bucketD_kernel,  dim3(NB),  blk, 0, stream, tmp, histTs, bsum2, bktTot, pcnt, row_ptr, pk, n, e, NB, nba);

    // ---- network ----
    hipLaunchKernelGGL(gemm1_kernel, gG, blk, 0, stream, x, W1, dinv, hs, n);
    hipLaunchKernelGGL(agg1_kernel,  gA, blk, 0, stream, hs, row_ptr, pk, dinv, b1, W2, hs2, n);
    hipLaunchKernelGGL(agg2_kernel,  gA, blk, 0, stream, hs2, row_ptr, pk, dinv, b2, Wl, bl, (float*)d_out, n);
}